// Round 12
// baseline (43316.846 us; speedup 1.0000x reference)
//
#include <hip/hip_runtime.h>

typedef __attribute__((ext_vector_type(4))) float f32x4;
typedef __attribute__((ext_vector_type(8))) short short8;
typedef __attribute__((ext_vector_type(2))) _Float16 half2v;
typedef __attribute__((ext_vector_type(4))) unsigned int u32x4;
typedef unsigned int u32;
typedef unsigned short u16;
typedef unsigned char u8;
typedef unsigned long long u64;

#define T_SEQ 4096
#define HDIM  2048
#define GDIM  8192   // 4*H
#define INDIM 512
#define NBLK  256    // recurrence blocks
#define FLAG_LINE 128  // bytes per block's flag line (8 used)

#if defined(__has_builtin)
#if __has_builtin(__builtin_amdgcn_fdot2)
#define HAS_FDOT2 1
#endif
#if __has_builtin(__builtin_amdgcn_exp2f)
#define EXP2F(x) __builtin_amdgcn_exp2f(x)   // v_exp_f32: 2^x, ~1 ulp
#endif
#endif
#ifndef HAS_FDOT2
#define HAS_FDOT2 0
#endif
#ifndef EXP2F
#define EXP2F(x) exp2f(x)
#endif

__device__ __forceinline__ u16 f2bf(float x) {
  u32 u = __float_as_uint(x);
  return (u16)((u + 0x7fffu + ((u >> 16) & 1u)) >> 16);  // RNE
}
__device__ __forceinline__ u16 f2h(float x) {
  _Float16 h = (_Float16)x;  // RNE
  return __builtin_bit_cast(unsigned short, h);
}
__device__ __forceinline__ float hlo(u32 u) {
  return (float)__builtin_bit_cast(_Float16, (unsigned short)(u & 0xffffu));
}
__device__ __forceinline__ float hhi(u32 u) {
  return (float)__builtin_bit_cast(_Float16, (unsigned short)(u >> 16));
}

// relaxed agent-scope accessors (single sc-bit op to coherence point, no
// invalidate/writeback). RULES (R6/R11 lessons): spin-poll traffic must stay
// ~65K transactions/sweep device-wide; 8B atomic loads do not coalesce.
__device__ __forceinline__ u64 aload64(const u64* p) {
  return __hip_atomic_load(p, __ATOMIC_RELAXED, __HIP_MEMORY_SCOPE_AGENT);
}
__device__ __forceinline__ void astoref(float* p, float v) {
  __hip_atomic_store(p, v, __ATOMIC_RELAXED, __HIP_MEMORY_SCOPE_AGENT);
}

// SWAR: mask of bytes in v that are zero (0x80 set per zero byte)
__device__ __forceinline__ u64 zbytes(u64 v) {
  return (v - 0x0101010101010101ULL) & ~v & 0x8080808080808080ULL;
}

// ---------------- prep kernels ----------------
__global__ void k_zero_f32(float* __restrict__ p, int n) {
  int i = blockIdx.x * blockDim.x + threadIdx.x;
  int st = gridDim.x * blockDim.x;
  for (; i < n; i += st) p[i] = 0.f;
}

__global__ void k_bias_sum(const float* __restrict__ a, const float* __restrict__ b,
                           float* __restrict__ o, int n) {
  int i = blockIdx.x * blockDim.x + threadIdx.x;
  if (i < n) o[i] = a[i] + b[i];
}

__global__ void k_cvt_bf16(const float* __restrict__ in, u16* __restrict__ out, int n) {
  int i = blockIdx.x * blockDim.x + threadIdx.x;
  int st = gridDim.x * blockDim.x;
  for (; i < n; i += st) out[i] = f2bf(in[i]);
}

// Pre-pack W_hh (fp32 [8192][2048]) into per-block striped f16 layout (R6-proven).
__global__ __launch_bounds__(512) void k_prep_whh(const float* __restrict__ w,
                                                  uint4* __restrict__ out) {
  const int bid = blockIdx.x;
  const int tid = threadIdx.x;
#pragma unroll
  for (int s = 0; s < 16; ++s) {
    int slot = s * 512 + tid;
    int l = slot & 63, r3 = slot >> 6;
    int g = r3 & 3, q = (r3 >> 2) & 3, wv = r3 >> 4;
    int grow = q * HDIM + bid * 8 + wv;
    const float* src = w + (size_t)grow * HDIM + l * 32 + g * 8;
    uint4 o;
    o.x = (u32)f2h(src[0]) | ((u32)f2h(src[1]) << 16);
    o.y = (u32)f2h(src[2]) | ((u32)f2h(src[3]) << 16);
    o.z = (u32)f2h(src[4]) | ((u32)f2h(src[5]) << 16);
    o.w = (u32)f2h(src[6]) | ((u32)f2h(src[7]) << 16);
    out[((size_t)bid * 16 + s) * 512 + tid] = o;
  }
}

// ---------------- bf16 MFMA GEMM:  C[M,N] = A[M,K] * B[N,K]^T + bias[N] ----------------
template <bool AF32>
__global__ __launch_bounds__(256) void gemm_bt_bias(
    const void* __restrict__ Av, const u16* __restrict__ B,
    const float* __restrict__ bias, float* __restrict__ C,
    int M, int N, int K)
{
  __shared__ u16 As[128 * 64];
  __shared__ u16 Bs[128 * 64];
  const int tid = threadIdx.x;
  const int m0 = blockIdx.y * 128;
  const int n0 = blockIdx.x * 128;
  const int w = tid >> 6;
  const int lane = tid & 63;
  const int wm = (w >> 1) * 64, wn = (w & 1) * 64;
  const int lr = lane & 15, lk = lane >> 4;

  f32x4 acc[4][4];
  f32x4 zero = {0.f, 0.f, 0.f, 0.f};
#pragma unroll
  for (int i = 0; i < 4; ++i)
#pragma unroll
    for (int j = 0; j < 4; ++j) acc[i][j] = zero;

  const int r = tid >> 1;
  const int sbase = (tid & 1) * 4;

  for (int kt = 0; kt < K; kt += 64) {
    uint4 va[4], vb[4];
#pragma unroll
    for (int s = 0; s < 4; ++s) {
      if constexpr (AF32) {
        const float* ga = (const float*)Av + (size_t)(m0 + r) * K + kt + (sbase + s) * 8;
        float4 f0 = *reinterpret_cast<const float4*>(ga);
        float4 f1 = *reinterpret_cast<const float4*>(ga + 4);
        va[s].x = (u32)f2bf(f0.x) | ((u32)f2bf(f0.y) << 16);
        va[s].y = (u32)f2bf(f0.z) | ((u32)f2bf(f0.w) << 16);
        va[s].z = (u32)f2bf(f1.x) | ((u32)f2bf(f1.y) << 16);
        va[s].w = (u32)f2bf(f1.z) | ((u32)f2bf(f1.w) << 16);
      } else {
        const u16* ga = (const u16*)Av + (size_t)(m0 + r) * K + kt + (sbase + s) * 8;
        va[s] = *reinterpret_cast<const uint4*>(ga);
      }
      const u16* gb = B + (size_t)(n0 + r) * K + kt + (sbase + s) * 8;
      vb[s] = *reinterpret_cast<const uint4*>(gb);
    }
    __syncthreads();
#pragma unroll
    for (int s = 0; s < 4; ++s) {
      int ps = (sbase + s) ^ (r & 7);
      *reinterpret_cast<uint4*>(&As[r * 64 + ps * 8]) = va[s];
      *reinterpret_cast<uint4*>(&Bs[r * 64 + ps * 8]) = vb[s];
    }
    __syncthreads();
#pragma unroll
    for (int k32 = 0; k32 < 2; ++k32) {
      short8 af[4], bg[4];
#pragma unroll
      for (int i = 0; i < 4; ++i) {
        int arow = wm + i * 16 + lr;
        int aslot = (k32 * 4 + lk) ^ (arow & 7);
        af[i] = *reinterpret_cast<const short8*>(&As[arow * 64 + aslot * 8]);
        int brow = wn + i * 16 + lr;
        int bslot = (k32 * 4 + lk) ^ (brow & 7);
        bg[i] = *reinterpret_cast<const short8*>(&Bs[brow * 64 + bslot * 8]);
      }
#pragma unroll
      for (int i = 0; i < 4; ++i)
#pragma unroll
        for (int j = 0; j < 4; ++j)
          acc[i][j] = __builtin_amdgcn_mfma_f32_16x16x32_bf16(af[i], bg[j], acc[i][j], 0, 0, 0);
    }
  }

#pragma unroll
  for (int j = 0; j < 4; ++j) {
    int gcol = n0 + wn + j * 16 + lr;
    float bv = bias[gcol];
#pragma unroll
    for (int i = 0; i < 4; ++i) {
      int grow = m0 + wm + i * 16 + lk * 4;
#pragma unroll
      for (int rr = 0; rr < 4; ++rr)
        C[(size_t)(grow + rr) * N + gcol] = acc[i][j][rr] + bv;
    }
  }
}

// ---------------- persistent LSTM recurrence ----------------
// R10 base (proven 2.80 us/step) with two cuts:
// (1) PER-WAVE BYTE FLAGS, no B3: each wave's lane0 stores h (write-through),
//     s_waitcnt vmcnt(0) (own store drained), then global_store_byte sc0 sc1
//     of tag (u8)(t+1) into its byte of the block's 8-byte flag word.
//     Hub (wave0) polls 4 flag lines/lane via aload64 (R10's proven 65K/sweep)
//     with a SWAR check accepting bytes in {t, t+1} (max skew 1, wrap-safe;
//     init zeros match t=0 whose h row is pre-zeroed). 2 barriers/step.
// (2) L0 h-fetch via global_load_dwordx4 sc0 sc1 (16B coalesced). Safe under
//     either sc semantic: hs0f rows are fresh lines, write-through pre-flag;
//     any cached copy was fetched post-flag => correct. L1 keeps the proven
//     ring + aload64 path (ring lines are reused => only cache-bypass safe).
__global__ __launch_bounds__(512, 1) void lstm_rec(
    const float* __restrict__ gx,    // [T][8192] input contribution (+biases)
    const uint4* __restrict__ wp,    // pre-packed f16 weights [256][16][512]
    float* __restrict__ hhist,       // rows of 2048 floats, row 0 pre-zeroed
    u8* __restrict__ flagb,          // [NBLK][FLAG_LINE] bytes, pre-zeroed
    int hmask, int sc_fetch, int T)
{
  __shared__ uint4 wlds[16 * 512];   // 128 KiB f16 weights
  __shared__ float4 hT[512];         // 8 KiB swizzled h row
  const int tid = threadIdx.x;
  const int bid = blockIdx.x;
  const int wv = tid >> 6;  // wave -> h element bid*8+wv
  const int l = tid & 63;

  // stage weights once (coalesced)
#pragma unroll
  for (int s = 0; s < 16; ++s)
    wlds[s * 512 + tid] = wp[((size_t)bid * 16 + s) * 512 + tid];
  __syncthreads();  // B0: wlds complete before the pre-poll prefetch reads it

  float c = 0.f;  // cell state (all lanes of each wave, consistent)

  for (int t = 0; t < T; ++t) {
    // weight prefetch into registers (overlaps the poll; R2/R8 idiom)
    uint4 wr[16];
#pragma unroll
    for (int s = 0; s < 16; ++s) wr[s] = wlds[(wv * 16 + s) * 64 + l];
#pragma unroll
    for (int s = 0; s < 16; ++s)
      asm volatile("" : "+v"(wr[s].x), "+v"(wr[s].y), "+v"(wr[s].z), "+v"(wr[s].w));

    // gx prefetch (cached; independent of h[t])
    float gv = 0.f;
    if (l < 4) gv = gx[(size_t)t * GDIM + l * HDIM + bid * 8 + wv];

    // ---- wait for h[t]: per-block hub, SWAR byte flags in {t, t+1} ----
    if (wv == 0) {
      const u64 rt  = 0x0101010101010101ULL * (u64)((u32)t & 0xFF);
      const u64 rt1 = 0x0101010101010101ULL * (u64)((u32)(t + 1) & 0xFF);
      const u64* f0 = (const u64*)(flagb + (size_t)(l * 4 + 0) * FLAG_LINE);
      const u64* f1 = (const u64*)(flagb + (size_t)(l * 4 + 1) * FLAG_LINE);
      const u64* f2 = (const u64*)(flagb + (size_t)(l * 4 + 2) * FLAG_LINE);
      const u64* f3 = (const u64*)(flagb + (size_t)(l * 4 + 3) * FLAG_LINE);
      const u64 ALL = 0x8080808080808080ULL;
      while (true) {
        u64 x0 = aload64(f0), x1 = aload64(f1), x2 = aload64(f2), x3 = aload64(f3);
        bool ok = ((zbytes(x0 ^ rt) | zbytes(x0 ^ rt1)) == ALL) &&
                  ((zbytes(x1 ^ rt) | zbytes(x1 ^ rt1)) == ALL) &&
                  ((zbytes(x2 ^ rt) | zbytes(x2 ^ rt1)) == ALL) &&
                  ((zbytes(x3 ^ rt) | zbytes(x3 ^ rt1)) == ALL);
        if (__all(ok)) break;
        __builtin_amdgcn_s_sleep(1);
      }
    }
    __syncthreads();  // B1: h[t] globally ready

    // stage h[t] into LDS
    {
      const float* hp = hhist + (size_t)(t & hmask) * HDIM + tid * 4;
      float4 hv;
      if (sc_fetch) {
        // coalesced 16B cache-bypass load (L0 fresh rows)
        u32x4 hu;
        asm volatile("global_load_dwordx4 %0, %1, off sc0 sc1\n\ts_waitcnt vmcnt(0)"
                     : "=v"(hu) : "v"(hp) : "memory");
        hv.x = __uint_as_float(hu.x);
        hv.y = __uint_as_float(hu.y);
        hv.z = __uint_as_float(hu.z);
        hv.w = __uint_as_float(hu.w);
      } else {
        // proven 8B atomic path (L1 ring: reused lines need true bypass)
        const u64* hsrc = (const u64*)hp;
        u64 d0 = aload64(&hsrc[0]);
        u64 d1 = aload64(&hsrc[1]);
        hv.x = __uint_as_float((u32)d0);
        hv.y = __uint_as_float((u32)(d0 >> 32));
        hv.z = __uint_as_float((u32)d1);
        hv.w = __uint_as_float((u32)(d1 >> 32));
      }
      int G2 = tid & 7, sb = tid >> 3;
      hT[G2 * 64 + (sb ^ ((G2 * 9) & 63))] = hv;
    }
    __syncthreads();  // B2: h staged

    // dot: 8 hT reads + fdot2 against prefetched weights
    float a0 = 0.f, a1 = 0.f, a2 = 0.f, a3 = 0.f;
#pragma unroll
    for (int g = 0; g < 4; ++g) {
      const int G0 = g * 2, G1 = g * 2 + 1;
      float4 h0 = hT[G0 * 64 + (l ^ ((G0 * 9) & 63))];
      float4 h1 = hT[G1 * 64 + (l ^ ((G1 * 9) & 63))];
#if HAS_FDOT2
      half2v p0, p1, p2, p3;
      p0[0] = (_Float16)h0.x; p0[1] = (_Float16)h0.y;
      p1[0] = (_Float16)h0.z; p1[1] = (_Float16)h0.w;
      p2[0] = (_Float16)h1.x; p2[1] = (_Float16)h1.y;
      p3[0] = (_Float16)h1.z; p3[1] = (_Float16)h1.w;
#define FD2(wu, pp, acc) __builtin_amdgcn_fdot2(__builtin_bit_cast(half2v, (wu)), (pp), (acc), false)
      a0 = FD2(wr[0 + g].x, p0, FD2(wr[0 + g].y, p1, FD2(wr[0 + g].z, p2, FD2(wr[0 + g].w, p3, a0))));
      a1 = FD2(wr[4 + g].x, p0, FD2(wr[4 + g].y, p1, FD2(wr[4 + g].z, p2, FD2(wr[4 + g].w, p3, a1))));
      a2 = FD2(wr[8 + g].x, p0, FD2(wr[8 + g].y, p1, FD2(wr[8 + g].z, p2, FD2(wr[8 + g].w, p3, a2))));
      a3 = FD2(wr[12 + g].x, p0, FD2(wr[12 + g].y, p1, FD2(wr[12 + g].z, p2, FD2(wr[12 + g].w, p3, a3))));
#undef FD2
#else
      a0 += hlo(wr[0 + g].x) * h0.x + hhi(wr[0 + g].x) * h0.y + hlo(wr[0 + g].y) * h0.z + hhi(wr[0 + g].y) * h0.w +
            hlo(wr[0 + g].z) * h1.x + hhi(wr[0 + g].z) * h1.y + hlo(wr[0 + g].w) * h1.z + hhi(wr[0 + g].w) * h1.w;
      a1 += hlo(wr[4 + g].x) * h0.x + hhi(wr[4 + g].x) * h0.y + hlo(wr[4 + g].y) * h0.z + hhi(wr[4 + g].y) * h0.w +
            hlo(wr[4 + g].z) * h1.x + hhi(wr[4 + g].z) * h1.y + hlo(wr[4 + g].w) * h1.z + hhi(wr[4 + g].w) * h1.w;
      a2 += hlo(wr[8 + g].x) * h0.x + hhi(wr[8 + g].x) * h0.y + hlo(wr[8 + g].y) * h0.z + hhi(wr[8 + g].y) * h0.w +
            hlo(wr[8 + g].z) * h1.x + hhi(wr[8 + g].z) * h1.y + hlo(wr[8 + g].w) * h1.z + hhi(wr[8 + g].w) * h1.w;
      a3 += hlo(wr[12 + g].x) * h0.x + hhi(wr[12 + g].x) * h0.y + hlo(wr[12 + g].y) * h0.z + hhi(wr[12 + g].y) * h0.w +
            hlo(wr[12 + g].z) * h1.x + hhi(wr[12 + g].z) * h1.y + hlo(wr[12 + g].w) * h1.z + hhi(wr[12 + g].w) * h1.w;
#endif
    }
    // 64-lane butterfly
#pragma unroll
    for (int m = 32; m >= 1; m >>= 1) {
      a0 += __shfl_xor(a0, m);
      a1 += __shfl_xor(a1, m);
      a2 += __shfl_xor(a2, m);
      a3 += __shfl_xor(a3, m);
    }
    float g0 = __shfl(gv, 0), g1 = __shfl(gv, 1), g2 = __shfl(gv, 2), g3 = __shfl(gv, 3);

    // wave-parallel gates (R10): lanes 0-3 one activation each via v_exp_f32
    {
      const float L2E = 1.44269504f;
      float pre = (l & 2) ? ((l & 1) ? a3 + g3 : a2 + g2)
                          : ((l & 1) ? a1 + g1 : a0 + g0);
      float k = (l == 2) ? 2.f * L2E : -L2E;
      float e = EXP2F(k * pre);
      float act = (l == 2) ? (1.f - 2.f / (e + 1.f)) : (1.f / (1.f + e));
      float i_ = __shfl(act, 0);
      float f_ = __shfl(act, 1);
      float gg = __shfl(act, 2);
      float o_ = __shfl(act, 3);
      c = f_ * c + i_ * gg;
      float th = 1.f - 2.f / (EXP2F(2.f * L2E * c) + 1.f);
      if (l == 0) {
        // publish: h store (write-through) -> own-store drain -> flag byte.
        astoref(&hhist[(size_t)((t + 1) & hmask) * HDIM + bid * 8 + wv],
                o_ * th);
        u8* fp = flagb + (size_t)bid * FLAG_LINE + wv;
        u32 tag = (u32)(t + 1) & 0xFF;
        asm volatile("s_waitcnt vmcnt(0)\n\tglobal_store_byte %0, %1, off sc0 sc1"
                     :: "v"(fp), "v"(tag) : "memory");
      }
    }
    // no B3: next iteration's B1 (flags==t+1 everywhere) provides all ordering
  }
}

// ---------------- heads: two 2048-dots ----------------
__global__ void k_heads(const float* __restrict__ h, const float* __restrict__ wt,
                        const float* __restrict__ bt, const float* __restrict__ wf,
                        const float* __restrict__ bfp, float* __restrict__ out) {
  int tid = threadIdx.x;  // 256
  float st = 0.f, sf = 0.f;
  for (int i = tid; i < HDIM; i += 256) {
    float hv = h[i];
    st += hv * wt[i];
    sf += hv * wf[i];
  }
#pragma unroll
  for (int m = 32; m >= 1; m >>= 1) {
    st += __shfl_xor(st, m, 64);
    sf += __shfl_xor(sf, m, 64);
  }
  __shared__ float ra[4], rb[4];
  if ((tid & 63) == 0) { ra[tid >> 6] = st; rb[tid >> 6] = sf; }
  __syncthreads();
  if (tid == 0) {
    out[0] = ra[0] + ra[1] + ra[2] + ra[3] + bt[0];
    out[1] = rb[0] + rb[1] + rb[2] + rb[3] + bfp[0];
  }
}

// ---------------- launch ----------------
extern "C" void kernel_launch(void* const* d_in, const int* in_sizes, int n_in,
                              void* d_out, int out_size, void* d_ws, size_t ws_size,
                              hipStream_t stream) {
  const float* x     = (const float*)d_in[0];
  const float* w_ih0 = (const float*)d_in[1];
  const float* w_hh0 = (const float*)d_in[2];
  const float* b_ih0 = (const float*)d_in[3];
  const float* b_hh0 = (const float*)d_in[4];
  const float* w_ih1 = (const float*)d_in[5];
  const float* w_hh1 = (const float*)d_in[6];
  const float* b_ih1 = (const float*)d_in[7];
  const float* b_hh1 = (const float*)d_in[8];
  const float* w_t   = (const float*)d_in[9];
  const float* b_t   = (const float*)d_in[10];
  const float* w_f   = (const float*)d_in[11];
  const float* b_f   = (const float*)d_in[12];

  // workspace layout (bytes), total ~236.2 MiB (known-good budget; R10 layout)
  char* p = (char*)d_ws;
  float* gx    = (float*)(p);                 // 134,217,728
  float* hs0f  = (float*)(p + 134217728);     // 4097*2048*4 = 33,562,624
  u16*   xb    = (u16*)  (p + 167780352);     // 4,194,304
  u16*   wb0   = (u16*)  (p + 171974656);     // 8,388,608
  u16*   wb1   = (u16*)  (p + 180363264);     // 33,554,432
  uint4* wprep = (uint4*)(p + 213917696);     // 33,554,432 (reused per layer)
  float* h1r   = (float*)(p + 247472128);     // 4*2048*4 = 32,768 (depth-4 ring)
  float* bias0 = (float*)(p + 247504896);     // 32,768
  float* bias1 = (float*)(p + 247537664);     // 32,768
  u8*    flags0b = (u8*) (p + 247570432);     // 256*128 = 32,768
  u8*    flags1b = (u8*) (p + 247603200);     // 256*128 = 32,768

  // init (re-run every launch => deterministic graph replay)
  k_zero_f32<<<8, 256, 0, stream>>>(hs0f, HDIM);        // h0 row 0 = 0
  k_zero_f32<<<32, 256, 0, stream>>>(h1r, 4 * HDIM);    // layer-1 ring = 0
  k_zero_f32<<<64, 256, 0, stream>>>((float*)flags0b, 2 * 8192);  // both flag slots
  k_bias_sum<<<GDIM / 256, 256, 0, stream>>>(b_ih0, b_hh0, bias0, GDIM);
  k_bias_sum<<<GDIM / 256, 256, 0, stream>>>(b_ih1, b_hh1, bias1, GDIM);
  k_cvt_bf16<<<1024, 256, 0, stream>>>(x, xb, T_SEQ * INDIM);
  k_cvt_bf16<<<1024, 256, 0, stream>>>(w_ih0, wb0, GDIM * INDIM);
  k_cvt_bf16<<<2048, 256, 0, stream>>>(w_ih1, wb1, GDIM * HDIM);

  // layer 0 (full history; sc_fetch=1 -> coalesced 16B cache-bypass h loads)
  k_prep_whh<<<NBLK, 512, 0, stream>>>(w_hh0, wprep);
  gemm_bt_bias<false><<<dim3(GDIM / 128, T_SEQ / 128), 256, 0, stream>>>(
      xb, wb0, bias0, gx, T_SEQ, GDIM, INDIM);
  lstm_rec<<<NBLK, 512, 0, stream>>>(gx, wprep, hs0f, flags0b,
                                     0x7fffffff, 1, T_SEQ);

  // layer 1 (A = hs0 fp32 rows 1..T, converted in GEMM staging; ring + atomics)
  gemm_bt_bias<true><<<dim3(GDIM / 128, T_SEQ / 128), 256, 0, stream>>>(
      hs0f + HDIM, wb1, bias1, gx, T_SEQ, GDIM, HDIM);
  k_prep_whh<<<NBLK, 512, 0, stream>>>(w_hh1, wprep);
  lstm_rec<<<NBLK, 512, 0, stream>>>(gx, wprep, h1r, flags1b, 3, 0, T_SEQ);

  // heads on h1[T] (ring row T&3 == 0)
  k_heads<<<1, 256, 0, stream>>>(h1r + (size_t)(T_SEQ & 3) * HDIM, w_t, b_t, w_f, b_f,
                                 (float*)d_out);
}

// Round 13
// 23606.070 us; speedup vs baseline: 1.8350x; 1.8350x over previous
//
#include <hip/hip_runtime.h>

typedef __attribute__((ext_vector_type(4))) float f32x4;
typedef __attribute__((ext_vector_type(8))) short short8;
typedef __attribute__((ext_vector_type(2))) _Float16 half2v;
typedef unsigned int u32;
typedef unsigned short u16;
typedef unsigned long long u64;

#define T_SEQ 4096
#define HDIM  2048
#define GDIM  8192   // 4*H
#define INDIM 512
#define NBLK  256    // recurrence blocks
#define FLAG_STRIDE 32  // ints -> 128B per flag line (spread; R5-proven)

#if defined(__has_builtin)
#if __has_builtin(__builtin_amdgcn_fdot2)
#define HAS_FDOT2 1
#endif
#if __has_builtin(__builtin_amdgcn_exp2f)
#define EXP2F(x) __builtin_amdgcn_exp2f(x)   // v_exp_f32: 2^x, ~1 ulp
#endif
#endif
#ifndef HAS_FDOT2
#define HAS_FDOT2 0
#endif
#ifndef EXP2F
#define EXP2F(x) exp2f(x)
#endif

__device__ __forceinline__ u16 f2bf(float x) {
  u32 u = __float_as_uint(x);
  return (u16)((u + 0x7fffu + ((u >> 16) & 1u)) >> 16);  // RNE
}
__device__ __forceinline__ u16 f2h(float x) {
  _Float16 h = (_Float16)x;  // RNE
  return __builtin_bit_cast(unsigned short, h);
}
__device__ __forceinline__ float hlo(u32 u) {
  return (float)__builtin_bit_cast(_Float16, (unsigned short)(u & 0xffffu));
}
__device__ __forceinline__ float hhi(u32 u) {
  return (float)__builtin_bit_cast(_Float16, (unsigned short)(u >> 16));
}

// relaxed agent-scope accessors (single sc-bit op to coherence point, no
// invalidate/writeback). RULES distilled from R6/R11/R12:
//  - spin-poll traffic must stay ~65K txn/sweep device-wide, few addrs/line;
//  - readiness must flip ATOMICALLY (one int store), not dribble in pieces;
//  - 8B atomic loads do not coalesce -> never use them as bulk data path in
//    a spin loop (one-shot burst per step is fine, proven R5-R10).
__device__ __forceinline__ int aload(const int* p) {
  return __hip_atomic_load(p, __ATOMIC_RELAXED, __HIP_MEMORY_SCOPE_AGENT);
}
__device__ __forceinline__ void astore(int* p, int v) {
  __hip_atomic_store(p, v, __ATOMIC_RELAXED, __HIP_MEMORY_SCOPE_AGENT);
}
__device__ __forceinline__ u64 aload64(const u64* p) {
  return __hip_atomic_load(p, __ATOMIC_RELAXED, __HIP_MEMORY_SCOPE_AGENT);
}
__device__ __forceinline__ void astoref(float* p, float v) {
  __hip_atomic_store(p, v, __ATOMIC_RELAXED, __HIP_MEMORY_SCOPE_AGENT);
}

// ---------------- prep kernels ----------------
__global__ void k_zero_f32(float* __restrict__ p, int n) {
  int i = blockIdx.x * blockDim.x + threadIdx.x;
  int st = gridDim.x * blockDim.x;
  for (; i < n; i += st) p[i] = 0.f;
}

__global__ void k_bias_sum(const float* __restrict__ a, const float* __restrict__ b,
                           float* __restrict__ o, int n) {
  int i = blockIdx.x * blockDim.x + threadIdx.x;
  if (i < n) o[i] = a[i] + b[i];
}

__global__ void k_cvt_bf16(const float* __restrict__ in, u16* __restrict__ out, int n) {
  int i = blockIdx.x * blockDim.x + threadIdx.x;
  int st = gridDim.x * blockDim.x;
  for (; i < n; i += st) out[i] = f2bf(in[i]);
}

// Pre-pack W_hh (fp32 [8192][2048]) into per-block striped f16 layout (R6-proven).
// slot = s*512 + tid: l = slot&63 (lane), r3 = slot>>6, g = r3&3 (k-subgroup),
// q = (r3>>2)&3 (gate), wv = r3>>4 (wave / h-element).
// gate row = q*2048 + bid*8 + wv ; k = l*32 + g*8 .. +8  (8 f16 -> uint4)
__global__ __launch_bounds__(512) void k_prep_whh(const float* __restrict__ w,
                                                  uint4* __restrict__ out) {
  const int bid = blockIdx.x;
  const int tid = threadIdx.x;
#pragma unroll
  for (int s = 0; s < 16; ++s) {
    int slot = s * 512 + tid;
    int l = slot & 63, r3 = slot >> 6;
    int g = r3 & 3, q = (r3 >> 2) & 3, wv = r3 >> 4;
    int grow = q * HDIM + bid * 8 + wv;
    const float* src = w + (size_t)grow * HDIM + l * 32 + g * 8;
    uint4 o;
    o.x = (u32)f2h(src[0]) | ((u32)f2h(src[1]) << 16);
    o.y = (u32)f2h(src[2]) | ((u32)f2h(src[3]) << 16);
    o.z = (u32)f2h(src[4]) | ((u32)f2h(src[5]) << 16);
    o.w = (u32)f2h(src[6]) | ((u32)f2h(src[7]) << 16);
    out[((size_t)bid * 16 + s) * 512 + tid] = o;
  }
}

// ---------------- bf16 MFMA GEMM:  C[M,N] = A[M,K] * B[N,K]^T + bias[N] ----------------
template <bool AF32>
__global__ __launch_bounds__(256) void gemm_bt_bias(
    const void* __restrict__ Av, const u16* __restrict__ B,
    const float* __restrict__ bias, float* __restrict__ C,
    int M, int N, int K)
{
  __shared__ u16 As[128 * 64];
  __shared__ u16 Bs[128 * 64];
  const int tid = threadIdx.x;
  const int m0 = blockIdx.y * 128;
  const int n0 = blockIdx.x * 128;
  const int w = tid >> 6;
  const int lane = tid & 63;
  const int wm = (w >> 1) * 64, wn = (w & 1) * 64;
  const int lr = lane & 15, lk = lane >> 4;

  f32x4 acc[4][4];
  f32x4 zero = {0.f, 0.f, 0.f, 0.f};
#pragma unroll
  for (int i = 0; i < 4; ++i)
#pragma unroll
    for (int j = 0; j < 4; ++j) acc[i][j] = zero;

  const int r = tid >> 1;           // 0..127 (tile row)
  const int sbase = (tid & 1) * 4;  // slot base (each slot = 8 bf16 = 16B)

  for (int kt = 0; kt < K; kt += 64) {
    uint4 va[4], vb[4];
#pragma unroll
    for (int s = 0; s < 4; ++s) {
      if constexpr (AF32) {
        const float* ga = (const float*)Av + (size_t)(m0 + r) * K + kt + (sbase + s) * 8;
        float4 f0 = *reinterpret_cast<const float4*>(ga);
        float4 f1 = *reinterpret_cast<const float4*>(ga + 4);
        va[s].x = (u32)f2bf(f0.x) | ((u32)f2bf(f0.y) << 16);
        va[s].y = (u32)f2bf(f0.z) | ((u32)f2bf(f0.w) << 16);
        va[s].z = (u32)f2bf(f1.x) | ((u32)f2bf(f1.y) << 16);
        va[s].w = (u32)f2bf(f1.z) | ((u32)f2bf(f1.w) << 16);
      } else {
        const u16* ga = (const u16*)Av + (size_t)(m0 + r) * K + kt + (sbase + s) * 8;
        va[s] = *reinterpret_cast<const uint4*>(ga);
      }
      const u16* gb = B + (size_t)(n0 + r) * K + kt + (sbase + s) * 8;
      vb[s] = *reinterpret_cast<const uint4*>(gb);
    }
    __syncthreads();  // previous iter's reads done before overwrite
#pragma unroll
    for (int s = 0; s < 4; ++s) {
      int ps = (sbase + s) ^ (r & 7);
      *reinterpret_cast<uint4*>(&As[r * 64 + ps * 8]) = va[s];
      *reinterpret_cast<uint4*>(&Bs[r * 64 + ps * 8]) = vb[s];
    }
    __syncthreads();
#pragma unroll
    for (int k32 = 0; k32 < 2; ++k32) {
      short8 af[4], bg[4];
#pragma unroll
      for (int i = 0; i < 4; ++i) {
        int arow = wm + i * 16 + lr;
        int aslot = (k32 * 4 + lk) ^ (arow & 7);
        af[i] = *reinterpret_cast<const short8*>(&As[arow * 64 + aslot * 8]);
        int brow = wn + i * 16 + lr;
        int bslot = (k32 * 4 + lk) ^ (brow & 7);
        bg[i] = *reinterpret_cast<const short8*>(&Bs[brow * 64 + bslot * 8]);
      }
#pragma unroll
      for (int i = 0; i < 4; ++i)
#pragma unroll
        for (int j = 0; j < 4; ++j)
          acc[i][j] = __builtin_amdgcn_mfma_f32_16x16x32_bf16(af[i], bg[j], acc[i][j], 0, 0, 0);
    }
  }

  // epilogue: C/D layout col = lane&15, row = (lane>>4)*4 + reg  [m89-verified]
#pragma unroll
  for (int j = 0; j < 4; ++j) {
    int gcol = n0 + wn + j * 16 + lr;
    float bv = bias[gcol];
#pragma unroll
    for (int i = 0; i < 4; ++i) {
      int grow = m0 + wm + i * 16 + lk * 4;
#pragma unroll
      for (int rr = 0; rr < 4; ++rr)
        C[(size_t)(grow + rr) * N + gcol] = acc[i][j][rr] + bv;
    }
  }
}

// ---------------- persistent LSTM recurrence (R10, proven 2.80 us/step) ------
// 256 blocks x 512 threads (8 waves). Weights f16 in LDS (128 KiB) + pre-poll
// register prefetch; fdot2 dot; per-block hub sync (wave0 polls all 256 spread
// flags, 4/lane, ~65K txn/sweep device-wide); aload64 h staging to swizzled
// LDS; wave-parallel exp2 gates; write-through h store; B3 + single int flag
// (atomic readiness flip -- R12 showed fragmenting this into per-wave bytes
// regresses 2x via extra poll sweeps + partial-line RMW traffic).
__global__ __launch_bounds__(512, 1) void lstm_rec(
    const float* __restrict__ gx,    // [T][8192] input contribution (+biases)
    const uint4* __restrict__ wp,    // pre-packed f16 weights [256][16][512]
    float* __restrict__ hhist,       // rows of 2048 floats, row 0 pre-zeroed
    int* __restrict__ flags,         // [NBLK*FLAG_STRIDE] spread, pre-zeroed
    int hmask, int T)
{
  __shared__ uint4 wlds[16 * 512];   // 128 KiB f16 weights
  __shared__ float4 hT[512];         // 8 KiB swizzled h row
  const int tid = threadIdx.x;
  const int bid = blockIdx.x;
  const int wv = tid >> 6;  // wave -> h element bid*8+wv
  const int l = tid & 63;

  // stage weights once (coalesced)
#pragma unroll
  for (int s = 0; s < 16; ++s)
    wlds[s * 512 + tid] = wp[((size_t)bid * 16 + s) * 512 + tid];
  __syncthreads();  // B0: wlds complete before the pre-poll prefetch reads it

  float c = 0.f;  // cell state (all lanes of each wave, kept consistent)

  for (int t = 0; t < T; ++t) {
    // weight prefetch into registers (overlaps the poll; R2-proven scalar pins)
    uint4 wr[16];
#pragma unroll
    for (int s = 0; s < 16; ++s) wr[s] = wlds[(wv * 16 + s) * 64 + l];
#pragma unroll
    for (int s = 0; s < 16; ++s)
      asm volatile("" : "+v"(wr[s].x), "+v"(wr[s].y), "+v"(wr[s].z), "+v"(wr[s].w));

    // gx prefetch (cached load, independent of h[t]; overlaps the poll)
    float gv = 0.f;
    if (l < 4) gv = gx[(size_t)t * GDIM + l * HDIM + bid * 8 + wv];

    // ---- wait for h[t]: per-block hub (wave0 polls all 256 flags, 4/lane) ----
    if (wv == 0) {
      const int* f0 = &flags[(l * 4 + 0) * FLAG_STRIDE];
      const int* f1 = &flags[(l * 4 + 1) * FLAG_STRIDE];
      const int* f2 = &flags[(l * 4 + 2) * FLAG_STRIDE];
      const int* f3 = &flags[(l * 4 + 3) * FLAG_STRIDE];
      while (true) {
        int m0 = min(min(aload(f0), aload(f1)), min(aload(f2), aload(f3)));
        if (__all(m0 >= t)) break;
        __builtin_amdgcn_s_sleep(1);
      }
    }
    __syncthreads();  // B1: h[t] globally ready

    // stage h[t] into LDS (relaxed-agent 8B loads -> coherence point, fresh;
    // one-shot burst per step, proven R5-R10)
    {
      const u64* hsrc = (const u64*)(hhist + (size_t)(t & hmask) * HDIM);
      u64 d0 = aload64(&hsrc[tid * 2]);
      u64 d1 = aload64(&hsrc[tid * 2 + 1]);
      float4 hv;
      hv.x = __uint_as_float((u32)d0);
      hv.y = __uint_as_float((u32)(d0 >> 32));
      hv.z = __uint_as_float((u32)d1);
      hv.w = __uint_as_float((u32)(d1 >> 32));
      int G2 = tid & 7, sb = tid >> 3;
      hT[G2 * 64 + (sb ^ ((G2 * 9) & 63))] = hv;
    }
    __syncthreads();  // B2: h staged

    // dot: 8 hT reads + fdot2 against prefetched weights
    float a0 = 0.f, a1 = 0.f, a2 = 0.f, a3 = 0.f;
#pragma unroll
    for (int g = 0; g < 4; ++g) {
      const int G0 = g * 2, G1 = g * 2 + 1;
      float4 h0 = hT[G0 * 64 + (l ^ ((G0 * 9) & 63))];
      float4 h1 = hT[G1 * 64 + (l ^ ((G1 * 9) & 63))];
#if HAS_FDOT2
      half2v p0, p1, p2, p3;
      p0[0] = (_Float16)h0.x; p0[1] = (_Float16)h0.y;
      p1[0] = (_Float16)h0.z; p1[1] = (_Float16)h0.w;
      p2[0] = (_Float16)h1.x; p2[1] = (_Float16)h1.y;
      p3[0] = (_Float16)h1.z; p3[1] = (_Float16)h1.w;
#define FD2(wu, pp, acc) __builtin_amdgcn_fdot2(__builtin_bit_cast(half2v, (wu)), (pp), (acc), false)
      a0 = FD2(wr[0 + g].x, p0, FD2(wr[0 + g].y, p1, FD2(wr[0 + g].z, p2, FD2(wr[0 + g].w, p3, a0))));
      a1 = FD2(wr[4 + g].x, p0, FD2(wr[4 + g].y, p1, FD2(wr[4 + g].z, p2, FD2(wr[4 + g].w, p3, a1))));
      a2 = FD2(wr[8 + g].x, p0, FD2(wr[8 + g].y, p1, FD2(wr[8 + g].z, p2, FD2(wr[8 + g].w, p3, a2))));
      a3 = FD2(wr[12 + g].x, p0, FD2(wr[12 + g].y, p1, FD2(wr[12 + g].z, p2, FD2(wr[12 + g].w, p3, a3))));
#undef FD2
#else
      a0 += hlo(wr[0 + g].x) * h0.x + hhi(wr[0 + g].x) * h0.y + hlo(wr[0 + g].y) * h0.z + hhi(wr[0 + g].y) * h0.w +
            hlo(wr[0 + g].z) * h1.x + hhi(wr[0 + g].z) * h1.y + hlo(wr[0 + g].w) * h1.z + hhi(wr[0 + g].w) * h1.w;
      a1 += hlo(wr[4 + g].x) * h0.x + hhi(wr[4 + g].x) * h0.y + hlo(wr[4 + g].y) * h0.z + hhi(wr[4 + g].y) * h0.w +
            hlo(wr[4 + g].z) * h1.x + hhi(wr[4 + g].z) * h1.y + hlo(wr[4 + g].w) * h1.z + hhi(wr[4 + g].w) * h1.w;
      a2 += hlo(wr[8 + g].x) * h0.x + hhi(wr[8 + g].x) * h0.y + hlo(wr[8 + g].y) * h0.z + hhi(wr[8 + g].y) * h0.w +
            hlo(wr[8 + g].z) * h1.x + hhi(wr[8 + g].z) * h1.y + hlo(wr[8 + g].w) * h1.z + hhi(wr[8 + g].w) * h1.w;
      a3 += hlo(wr[12 + g].x) * h0.x + hhi(wr[12 + g].x) * h0.y + hlo(wr[12 + g].y) * h0.z + hhi(wr[12 + g].y) * h0.w +
            hlo(wr[12 + g].z) * h1.x + hhi(wr[12 + g].z) * h1.y + hlo(wr[12 + g].w) * h1.z + hhi(wr[12 + g].w) * h1.w;
#endif
    }
    // 64-lane butterfly: all lanes end with the 4 gate sums
#pragma unroll
    for (int m = 32; m >= 1; m >>= 1) {
      a0 += __shfl_xor(a0, m);
      a1 += __shfl_xor(a1, m);
      a2 += __shfl_xor(a2, m);
      a3 += __shfl_xor(a3, m);
    }
    float g0 = __shfl(gv, 0), g1 = __shfl(gv, 1), g2 = __shfl(gv, 2), g3 = __shfl(gv, 3);

    // wave-parallel gates: lane0->i (sigmoid), lane1->f (sigmoid),
    // lane2->g (tanh), lane3->o (sigmoid); single v_exp_f32 per lane.
    // sigmoid(x) = 1/(1+exp2(-x*log2e)); tanh(x) = 1 - 2/(exp2(2x*log2e)+1)
    {
      const float L2E = 1.44269504f;
      float pre = (l & 2) ? ((l & 1) ? a3 + g3 : a2 + g2)
                          : ((l & 1) ? a1 + g1 : a0 + g0);
      float k = (l == 2) ? 2.f * L2E : -L2E;
      float e = EXP2F(k * pre);
      float act = (l == 2) ? (1.f - 2.f / (e + 1.f)) : (1.f / (1.f + e));
      float i_ = __shfl(act, 0);
      float f_ = __shfl(act, 1);
      float gg = __shfl(act, 2);
      float o_ = __shfl(act, 3);
      c = f_ * c + i_ * gg;  // all lanes redundantly (consistent arithmetic)
      float th = 1.f - 2.f / (EXP2F(2.f * L2E * c) + 1.f);
      float hval = o_ * th;
      if (l == 0) {
        // write-through store: at coherence point once this wave's vmcnt drains
        astoref(&hhist[(size_t)((t + 1) & hmask) * HDIM + bid * 8 + wv], hval);
      }
    }
    __syncthreads();  // B3: every wave drained vmcnt(0) before s_barrier
    if (tid == 0) astore(&flags[bid * FLAG_STRIDE], t + 1);
  }
}

// ---------------- heads: two 2048-dots ----------------
__global__ void k_heads(const float* __restrict__ h, const float* __restrict__ wt,
                        const float* __restrict__ bt, const float* __restrict__ wf,
                        const float* __restrict__ bfp, float* __restrict__ out) {
  int tid = threadIdx.x;  // 256
  float st = 0.f, sf = 0.f;
  for (int i = tid; i < HDIM; i += 256) {
    float hv = h[i];
    st += hv * wt[i];
    sf += hv * wf[i];
  }
#pragma unroll
  for (int m = 32; m >= 1; m >>= 1) {
    st += __shfl_xor(st, m, 64);
    sf += __shfl_xor(sf, m, 64);
  }
  __shared__ float ra[4], rb[4];
  if ((tid & 63) == 0) { ra[tid >> 6] = st; rb[tid >> 6] = sf; }
  __syncthreads();
  if (tid == 0) {
    out[0] = ra[0] + ra[1] + ra[2] + ra[3] + bt[0];
    out[1] = rb[0] + rb[1] + rb[2] + rb[3] + bfp[0];
  }
}

// ---------------- launch ----------------
extern "C" void kernel_launch(void* const* d_in, const int* in_sizes, int n_in,
                              void* d_out, int out_size, void* d_ws, size_t ws_size,
                              hipStream_t stream) {
  const float* x     = (const float*)d_in[0];
  const float* w_ih0 = (const float*)d_in[1];
  const float* w_hh0 = (const float*)d_in[2];
  const float* b_ih0 = (const float*)d_in[3];
  const float* b_hh0 = (const float*)d_in[4];
  const float* w_ih1 = (const float*)d_in[5];
  const float* w_hh1 = (const float*)d_in[6];
  const float* b_ih1 = (const float*)d_in[7];
  const float* b_hh1 = (const float*)d_in[8];
  const float* w_t   = (const float*)d_in[9];
  const float* b_t   = (const float*)d_in[10];
  const float* w_f   = (const float*)d_in[11];
  const float* b_f   = (const float*)d_in[12];

  // workspace layout (bytes), total ~236.2 MiB (known-good budget; R5 layout)
  char* p = (char*)d_ws;
  float* gx    = (float*)(p);                 // 134,217,728
  float* hs0f  = (float*)(p + 134217728);     // 4097*2048*4 = 33,562,624
  u16*   xb    = (u16*)  (p + 167780352);     // 4,194,304
  u16*   wb0   = (u16*)  (p + 171974656);     // 8,388,608
  u16*   wb1   = (u16*)  (p + 180363264);     // 33,554,432
  uint4* wprep = (uint4*)(p + 213917696);     // 33,554,432 (reused per layer)
  float* h1r   = (float*)(p + 247472128);     // 4*2048*4 = 32,768 (depth-4 ring)
  float* bias0 = (float*)(p + 247504896);     // 32,768
  float* bias1 = (float*)(p + 247537664);     // 32,768
  int*   flags0= (int*)  (p + 247570432);     // spread [256*32] ints = 32,768
  int*   flags1= (int*)  (p + 247603200);     // spread [256*32] ints = 32,768

  // init (re-run every launch => deterministic graph replay)
  k_zero_f32<<<8, 256, 0, stream>>>(hs0f, HDIM);        // h0 row 0 = 0
  k_zero_f32<<<32, 256, 0, stream>>>(h1r, 4 * HDIM);    // layer-1 ring = 0
  k_zero_f32<<<64, 256, 0, stream>>>((float*)flags0, 2 * NBLK * FLAG_STRIDE);
  k_bias_sum<<<GDIM / 256, 256, 0, stream>>>(b_ih0, b_hh0, bias0, GDIM);
  k_bias_sum<<<GDIM / 256, 256, 0, stream>>>(b_ih1, b_hh1, bias1, GDIM);
  k_cvt_bf16<<<1024, 256, 0, stream>>>(x, xb, T_SEQ * INDIM);
  k_cvt_bf16<<<1024, 256, 0, stream>>>(w_ih0, wb0, GDIM * INDIM);
  k_cvt_bf16<<<2048, 256, 0, stream>>>(w_ih1, wb1, GDIM * HDIM);

  // layer 0
  k_prep_whh<<<NBLK, 512, 0, stream>>>(w_hh0, wprep);
  gemm_bt_bias<false><<<dim3(GDIM / 128, T_SEQ / 128), 256, 0, stream>>>(
      xb, wb0, bias0, gx, T_SEQ, GDIM, INDIM);
  lstm_rec<<<NBLK, 512, 0, stream>>>(gx, wprep, hs0f, flags0, 0x7fffffff, T_SEQ);

  // layer 1 (A = hs0 fp32 rows 1..T, converted in GEMM staging)
  gemm_bt_bias<true><<<dim3(GDIM / 128, T_SEQ / 128), 256, 0, stream>>>(
      hs0f + HDIM, wb1, bias1, gx, T_SEQ, GDIM, HDIM);
  k_prep_whh<<<NBLK, 512, 0, stream>>>(w_hh1, wprep);
  lstm_rec<<<NBLK, 512, 0, stream>>>(gx, wprep, h1r, flags1, 3, T_SEQ);

  // heads on h1[T] (ring row T&3 == 0)
  k_heads<<<1, 256, 0, stream>>>(h1r + (size_t)(T_SEQ & 3) * HDIM, w_t, b_t, w_f, b_f,
                                 (float*)d_out);
}